// Round 5
// baseline (389.389 us; speedup 1.0000x reference)
//
#include <hip/hip_runtime.h>
#include <hip/hip_cooperative_groups.h>

namespace cg = cooperative_groups;

#define NN 8192
#define DD 128
// ALPHA * log2(e)
#define C2 72.13475204444817f
#define LN2 0.6931471805599453f

typedef __attribute__((ext_vector_type(8))) __bf16 bf16x8;
typedef __attribute__((ext_vector_type(4))) float f32x4;

#if __has_builtin(__builtin_amdgcn_exp2f)
#define EXP2F(x) __builtin_amdgcn_exp2f(x)
#else
#define EXP2F(x) exp2f(x)
#endif
#if __has_builtin(__builtin_amdgcn_sqrtf)
#define SQRTF(x) __builtin_amdgcn_sqrtf(x)
#else
#define SQRTF(x) sqrtf(x)
#endif
#if __has_builtin(__builtin_amdgcn_logf)
#define LOG2F(x) __builtin_amdgcn_logf(x)  // v_log_f32 = log base 2
#else
#define LOG2F(x) log2f(x)
#endif

__device__ __forceinline__ unsigned short f2bf(float f) {
  unsigned u = __float_as_uint(f);
  u += 0x7FFFu + ((u >> 16) & 1u);  // RNE
  return (unsigned short)(u >> 16);
}

// ======================= cooperative mega-kernel ===========================
// 512 blocks x 256 threads = exactly 2 blocks/CU co-resident — the occupancy
// R1/R3 MEASURED for this register footprint (124 VGPR + 64 AGPR unified).
// No launch_bounds cap (R2 lesson: forcing 128 regs on a ~188-reg structure
// spills 300 MB; R4 lesson: demanding 4 blocks/CU fails the cooperative
// co-residency check and the kernel never launches).
__global__ void mega_kernel(const float* __restrict__ x,
                            unsigned short* __restrict__ xbf,
                            float* __restrict__ sq, float* __restrict__ pos_e,
                            float* __restrict__ pos_d,
                            float* __restrict__ tot_e,
                            float* __restrict__ scal, float* __restrict__ out) {
  cg::grid_group grid = cg::this_grid();
  const int tid = threadIdx.x;
  const int lane = tid & 63;
  const int w = tid >> 6;  // wave 0..3
  const int b = blockIdx.x;

  __shared__ float xs[16][128];  // 8 KB: 2 classes = 16 rows
  __shared__ float sqs[16];
  __shared__ float part[4];
  __shared__ float s1[256], s2[256];

  // ===== phase A: bf16 convert + row norms + exact fp32 positives =========
  // block b: rows 16b..16b+15 (classes 2b, 2b+1); wave w: rows 4w..4w+3
  // (all 4 rows of a wave lie in one class -> partner loop is wave-uniform).
  {
#pragma unroll
    for (int rr = 0; rr < 4; ++rr) {
      int li = w * 4 + rr;
      int i = b * 16 + li;
      const float* xr = x + (size_t)i * DD;
      float a = xr[lane], cc = xr[lane + 64];
      xs[li][lane] = a;
      xs[li][lane + 64] = cc;
      float s = __fmaf_rn(a, a, cc * cc);
#pragma unroll
      for (int m = 32; m; m >>= 1) s += __shfl_xor(s, m, 64);
      if (lane == 0) {
        sq[i] = s;
        sqs[li] = s;
      }
      unsigned short* o = xbf + (size_t)i * DD;
      o[lane] = f2bf(a);
      o[lane + 64] = f2bf(cc);
    }
    if (tid < 16) tot_e[b * 16 + tid] = 0.f;
    if (b == 0 && tid == 0) scal[0] = 0.f;
    __syncthreads();
#pragma unroll
    for (int rr = 0; rr < 4; ++rr) {
      int li = w * 4 + rr;
      int i = b * 16 + li;
      int lb = li & ~7;  // class base within the 16 local rows
      float a = xs[li][lane], cc = xs[li][lane + 64];
      float sqi = sqs[li];
      float pe = 0.f, pd = 0.f;
#pragma unroll
      for (int j = lb; j < lb + 8; ++j) {
        if (j == li) continue;  // wave-uniform
        float dot = __fmaf_rn(a, xs[j][lane], cc * xs[j][lane + 64]);
#pragma unroll
        for (int m = 32; m; m >>= 1) dot += __shfl_xor(dot, m, 64);
        float d2 = fmaxf(__fmaf_rn(-2.f, dot, sqi + sqs[j]), 1e-12f);
        float dist = SQRTF(d2);
        pe += EXP2F(__fmaf_rn(dist, -C2, C2));
        pd += dist;
      }
      if (lane == 0) {
        pos_e[i] = pe;
        pos_d[i] = pd;
      }
    }
  }
  __threadfence();  // release xbf/sq before cross-XCD consumption
  grid.sync();
  __threadfence();  // acquire side: drop stale cached lines

  // ===== phase B: MFMA tiles (R1-proven 47us structure) ===================
  // logical grid (64,8): bx = rows 128, by = cols 1024. 4 waves in 2x2;
  // each wave a 64x64 tile = 4x4 of 16x16x32 MFMA, jt loop 8 x 128 cols.
  {
    const int bx = b & 63, by = b >> 6;
    const int q = lane >> 4, c = lane & 15;
    const int I0 = bx * 128 + (w >> 1) * 64;
    const int Jc = by * 1024 + (w & 1) * 64;

    bf16x8 afrag[4][4];
#pragma unroll
    for (int rb = 0; rb < 4; ++rb) {
      const unsigned short* ap = xbf + (size_t)(I0 + rb * 16 + c) * DD + q * 8;
#pragma unroll
      for (int ks = 0; ks < 4; ++ks)
        afrag[rb][ks] = *(const bf16x8*)(ap + ks * 32);
    }
    float sqi[16];
#pragma unroll
    for (int rb = 0; rb < 4; ++rb)
#pragma unroll
      for (int r = 0; r < 4; ++r)
        sqi[rb * 4 + r] = sq[I0 + rb * 16 + q * 4 + r];

    float tote[16];
#pragma unroll
    for (int k = 0; k < 16; ++k) tote[k] = 0.f;
    float totd = 0.f;

    for (int jt = 0; jt < 8; ++jt) {
      int J0 = Jc + jt * 128;
      f32x4 acc[4][4];
#pragma unroll
      for (int rb = 0; rb < 4; ++rb)
#pragma unroll
        for (int cb = 0; cb < 4; ++cb)
          acc[rb][cb] = (f32x4){0.f, 0.f, 0.f, 0.f};
#pragma unroll
      for (int ks = 0; ks < 4; ++ks) {
        bf16x8 bfr[4];
#pragma unroll
        for (int cb = 0; cb < 4; ++cb)
          bfr[cb] = *(const bf16x8*)(xbf + (size_t)(J0 + cb * 16 + c) * DD +
                                     ks * 32 + q * 8);
#pragma unroll
        for (int rb = 0; rb < 4; ++rb)
#pragma unroll
          for (int cb = 0; cb < 4; ++cb)
            acc[rb][cb] = __builtin_amdgcn_mfma_f32_16x16x32_bf16(
                afrag[rb][ks], bfr[cb], acc[rb][cb], 0, 0, 0);
      }
      // epilogue: C/D mapping col = lane&15, row = q*4 + reg (m89-verified)
      float sqj[4];
#pragma unroll
      for (int cb = 0; cb < 4; ++cb) sqj[cb] = sq[J0 + cb * 16 + c];
#pragma unroll
      for (int rb = 0; rb < 4; ++rb) {
#pragma unroll
        for (int cb = 0; cb < 4; ++cb) {
          bool diag = (I0 + rb * 16) == (J0 + cb * 16);
#pragma unroll
          for (int r = 0; r < 4; ++r) {
            float d2 = fmaxf(
                __fmaf_rn(-2.f, acc[rb][cb][r], sqi[rb * 4 + r] + sqj[cb]),
                1e-12f);
            float dist = SQRTF(d2);
            float ex = EXP2F(__fmaf_rn(dist, -C2, C2));
            if (diag && (q * 4 + r) == c) {  // exclude self-pair
              ex = 0.f;
              dist = 0.f;
            }
            tote[rb * 4 + r] += ex;
            totd += dist;
          }
        }
      }
    }

#pragma unroll
    for (int k = 0; k < 16; ++k) {
      float v = tote[k];
      v += __shfl_xor(v, 1, 64);
      v += __shfl_xor(v, 2, 64);
      v += __shfl_xor(v, 4, 64);
      v += __shfl_xor(v, 8, 64);
      tote[k] = v;
    }
    if (c == 0) {
#pragma unroll
      for (int rb = 0; rb < 4; ++rb)
#pragma unroll
        for (int r = 0; r < 4; ++r)
          atomicAdd(&tot_e[I0 + rb * 16 + q * 4 + r], tote[rb * 4 + r]);
    }
#pragma unroll
    for (int m = 32; m; m >>= 1) totd += __shfl_xor(totd, m, 64);
    if (lane == 0) part[w] = totd;
    __syncthreads();
    if (tid == 0) atomicAdd(&scal[0], part[0] + part[1] + part[2] + part[3]);
  }
  __threadfence();
  grid.sync();

  // ===== phase C: final scalars (block 0) =================================
  if (b == 0) {
    float lsum = 0.f, pdsum = 0.f;
    for (int i = tid; i < NN; i += 256) {
      // agent-scope atomic loads: coherent reads of cross-XCD accumulations
      float p = __hip_atomic_load(&pos_e[i], __ATOMIC_RELAXED,
                                  __HIP_MEMORY_SCOPE_AGENT);
      float t = __hip_atomic_load(&tot_e[i], __ATOMIC_RELAXED,
                                  __HIP_MEMORY_SCOPE_AGENT);
      float pdv = __hip_atomic_load(&pos_d[i], __ATOMIC_RELAXED,
                                    __HIP_MEMORY_SCOPE_AGENT);
      float denom = __fmaf_rn(0.5f, t - p, p);  // p + 0.5*(tot - p)
      lsum += LOG2F(denom) - LOG2F(p);          // -log2(p/(p+neg))
      pdsum += pdv;
    }
    s1[tid] = lsum;
    s2[tid] = pdsum;
    __syncthreads();
    for (int ww = 128; ww; ww >>= 1) {
      if (tid < ww) {
        s1[tid] += s1[tid + ww];
        s2[tid] += s2[tid + ww];
      }
      __syncthreads();
    }
    if (tid == 0) {
      float sc = __hip_atomic_load(&scal[0], __ATOMIC_RELAXED,
                                   __HIP_MEMORY_SCOPE_AGENT);
      out[0] = s1[0] * LN2 / (float)NN;                   // loss
      out[1] = 1.0f;                                      // prec
      out[2] = s2[0] / (float)(NN * 7);                   // pos_d
      out[3] = (sc - s2[0]) / ((float)NN * 8184.f);       // neg_d
    }
  }
}

// ======================= fallback path (R1/R3-proven) ======================
__global__ __launch_bounds__(512) void prep_pos_kernel(
    const float* __restrict__ x, unsigned short* __restrict__ xbf,
    float* __restrict__ sq, float* __restrict__ pos_e,
    float* __restrict__ pos_d, float* __restrict__ tot_e,
    float* __restrict__ scal) {
  int w = threadIdx.x >> 6;
  int lane = threadIdx.x & 63;
  int i = blockIdx.x * 8 + w;

  __shared__ float xs[8][128];
  __shared__ float sqs[8];

  const float* xr = x + (size_t)i * DD;
  float a = xr[lane], cc = xr[lane + 64];
  xs[w][lane] = a;
  xs[w][lane + 64] = cc;

  float s = __fmaf_rn(a, a, cc * cc);
#pragma unroll
  for (int m = 32; m; m >>= 1) s += __shfl_xor(s, m, 64);
  if (lane == 0) {
    sq[i] = s;
    sqs[w] = s;
  }
  unsigned short* o = xbf + (size_t)i * DD;
  o[lane] = f2bf(a);
  o[lane + 64] = f2bf(cc);
  if (lane == 1) tot_e[i] = 0.f;
  if (blockIdx.x == 0 && threadIdx.x == 0) scal[0] = 0.f;

  __syncthreads();
  float sqi = sqs[w];
  float pe = 0.f, pd = 0.f;
  for (int j = 0; j < 8; ++j) {
    if (j == w) continue;
    float dot = __fmaf_rn(a, xs[j][lane], cc * xs[j][lane + 64]);
#pragma unroll
    for (int m = 32; m; m >>= 1) dot += __shfl_xor(dot, m, 64);
    float d2 = fmaxf(__fmaf_rn(-2.f, dot, sqi + sqs[j]), 1e-12f);
    float dist = SQRTF(d2);
    pe += EXP2F(__fmaf_rn(dist, -C2, C2));
    pd += dist;
  }
  if (lane == 0) {
    pos_e[i] = pe;
    pos_d[i] = pd;
  }
}

__global__ __launch_bounds__(256, 2) void tile_kernel(
    const unsigned short* __restrict__ xbf, const float* __restrict__ sq,
    float* __restrict__ tot_e, float* __restrict__ scal) {
  int lane = threadIdx.x & 63;
  int wave = threadIdx.x >> 6;
  int q = lane >> 4, c = lane & 15;
  int I0 = blockIdx.x * 128 + (wave >> 1) * 64;
  int Jc = blockIdx.y * 1024 + (wave & 1) * 64;

  bf16x8 afrag[4][4];
#pragma unroll
  for (int rb = 0; rb < 4; ++rb) {
    const unsigned short* ap = xbf + (size_t)(I0 + rb * 16 + c) * DD + q * 8;
#pragma unroll
    for (int ks = 0; ks < 4; ++ks)
      afrag[rb][ks] = *(const bf16x8*)(ap + ks * 32);
  }
  float sqi[16];
#pragma unroll
  for (int rb = 0; rb < 4; ++rb)
#pragma unroll
    for (int r = 0; r < 4; ++r)
      sqi[rb * 4 + r] = sq[I0 + rb * 16 + q * 4 + r];

  float tote[16];
#pragma unroll
  for (int k = 0; k < 16; ++k) tote[k] = 0.f;
  float totd = 0.f;

  for (int jt = 0; jt < 8; ++jt) {
    int J0 = Jc + jt * 128;
    f32x4 acc[4][4];
#pragma unroll
    for (int rb = 0; rb < 4; ++rb)
#pragma unroll
      for (int cb = 0; cb < 4; ++cb) acc[rb][cb] = (f32x4){0.f, 0.f, 0.f, 0.f};
#pragma unroll
    for (int ks = 0; ks < 4; ++ks) {
      bf16x8 bfr[4];
#pragma unroll
      for (int cb = 0; cb < 4; ++cb)
        bfr[cb] = *(const bf16x8*)(xbf + (size_t)(J0 + cb * 16 + c) * DD +
                                   ks * 32 + q * 8);
#pragma unroll
      for (int rb = 0; rb < 4; ++rb)
#pragma unroll
        for (int cb = 0; cb < 4; ++cb)
          acc[rb][cb] = __builtin_amdgcn_mfma_f32_16x16x32_bf16(
              afrag[rb][ks], bfr[cb], acc[rb][cb], 0, 0, 0);
    }
    float sqj[4];
#pragma unroll
    for (int cb = 0; cb < 4; ++cb) sqj[cb] = sq[J0 + cb * 16 + c];
#pragma unroll
    for (int rb = 0; rb < 4; ++rb) {
#pragma unroll
      for (int cb = 0; cb < 4; ++cb) {
        bool diag = (I0 + rb * 16) == (J0 + cb * 16);
#pragma unroll
        for (int r = 0; r < 4; ++r) {
          float d2 = fmaxf(
              __fmaf_rn(-2.f, acc[rb][cb][r], sqi[rb * 4 + r] + sqj[cb]),
              1e-12f);
          float dist = SQRTF(d2);
          float ex = EXP2F(__fmaf_rn(dist, -C2, C2));
          if (diag && (q * 4 + r) == c) {
            ex = 0.f;
            dist = 0.f;
          }
          tote[rb * 4 + r] += ex;
          totd += dist;
        }
      }
    }
  }

#pragma unroll
  for (int k = 0; k < 16; ++k) {
    float v = tote[k];
    v += __shfl_xor(v, 1, 64);
    v += __shfl_xor(v, 2, 64);
    v += __shfl_xor(v, 4, 64);
    v += __shfl_xor(v, 8, 64);
    tote[k] = v;
  }
  if (c == 0) {
#pragma unroll
    for (int rb = 0; rb < 4; ++rb)
#pragma unroll
      for (int r = 0; r < 4; ++r)
        atomicAdd(&tot_e[I0 + rb * 16 + q * 4 + r], tote[rb * 4 + r]);
  }
#pragma unroll
  for (int m = 32; m; m >>= 1) totd += __shfl_xor(totd, m, 64);
  __shared__ float part[4];
  if (lane == 0) part[wave] = totd;
  __syncthreads();
  if (threadIdx.x == 0)
    atomicAdd(&scal[0], part[0] + part[1] + part[2] + part[3]);
}

__global__ void fin_kernel(const float* __restrict__ tot_e,
                           const float* __restrict__ pos_e,
                           const float* __restrict__ pos_d,
                           const float* __restrict__ scal,
                           float* __restrict__ out) {
  int tid = threadIdx.x;
  float lsum = 0.f, pdsum = 0.f;
  for (int i = tid; i < NN; i += 256) {
    float p = pos_e[i];
    float t = tot_e[i];
    float denom = __fmaf_rn(0.5f, t - p, p);
    lsum += LOG2F(denom) - LOG2F(p);
    pdsum += pos_d[i];
  }
  __shared__ float s1[256], s2[256];
  s1[tid] = lsum;
  s2[tid] = pdsum;
  __syncthreads();
  for (int w = 128; w; w >>= 1) {
    if (tid < w) {
      s1[tid] += s1[tid + w];
      s2[tid] += s2[tid + w];
    }
    __syncthreads();
  }
  if (tid == 0) {
    out[0] = s1[0] * LN2 / (float)NN;
    out[1] = 1.0f;
    out[2] = s2[0] / (float)(NN * 7);
    out[3] = (scal[0] - s2[0]) / ((float)NN * 8184.f);
  }
}

extern "C" void kernel_launch(void* const* d_in, const int* in_sizes, int n_in,
                              void* d_out, int out_size, void* d_ws,
                              size_t ws_size, hipStream_t stream) {
  const float* x = (const float*)d_in[0];
  float* out = (float*)d_out;
  char* ws = (char*)d_ws;

  unsigned short* xbf = (unsigned short*)ws;       // 2 MB
  float* sq = (float*)(ws + (size_t)NN * DD * 2);  // 32 KB each
  float* tot_e = sq + NN;
  float* pos_e = tot_e + NN;
  float* pos_d = pos_e + NN;
  float* scal = pos_d + NN;  // [0] = total dist sum

  void* args[] = {(void*)&x,     (void*)&xbf,   (void*)&sq,
                  (void*)&pos_e, (void*)&pos_d, (void*)&tot_e,
                  (void*)&scal,  (void*)&out};
  hipError_t err = hipLaunchCooperativeKernel(
      (const void*)mega_kernel, dim3(512), dim3(256), args, 0, stream);
  if (err != hipSuccess) {
    // deterministic fallback: proven 3-kernel path (same math, R1/R3)
    prep_pos_kernel<<<NN / 8, 512, 0, stream>>>(x, xbf, sq, pos_e, pos_d,
                                                tot_e, scal);
    tile_kernel<<<dim3(64, 8), 256, 0, stream>>>(xbf, sq, tot_e, scal);
    fin_kernel<<<1, 256, 0, stream>>>(tot_e, pos_e, pos_d, scal, out);
  }
}

// Round 6
// 305.665 us; speedup vs baseline: 1.2739x; 1.2739x over previous
//
#include <hip/hip_runtime.h>
#include <hip/hip_cooperative_groups.h>

namespace cg = cooperative_groups;

#define NN 8192
#define DD 128
// ALPHA * log2(e)
#define C2 72.13475204444817f
#define LN2 0.6931471805599453f

typedef __attribute__((ext_vector_type(8))) __bf16 bf16x8;
typedef __attribute__((ext_vector_type(4))) float f32x4;

#if __has_builtin(__builtin_amdgcn_exp2f)
#define EXP2F(x) __builtin_amdgcn_exp2f(x)
#else
#define EXP2F(x) exp2f(x)
#endif
#if __has_builtin(__builtin_amdgcn_sqrtf)
#define SQRTF(x) __builtin_amdgcn_sqrtf(x)
#else
#define SQRTF(x) sqrtf(x)
#endif
#if __has_builtin(__builtin_amdgcn_logf)
#define LOG2F(x) __builtin_amdgcn_logf(x)  // v_log_f32 = log base 2
#else
#define LOG2F(x) log2f(x)
#endif

__device__ __forceinline__ unsigned short f2bf(float f) {
  unsigned u = __float_as_uint(f);
  u += 0x7FFFu + ((u >> 16) & 1u);  // RNE
  return (unsigned short)(u >> 16);
}

// ======================= cooperative mega-kernel ===========================
// 512 blocks x 256 threads = 2 blocks/CU co-resident (the occupancy R1/R3
// measured for this 124-VGPR + 64-AGPR footprint).
// __launch_bounds__(256,2) is ESSENTIAL: without it HIP compiles for a
// worst-case 1024-thread block -> 128-reg unified cap -> 64 VGPR + 64 AGPR
// -> ~300 MB scratch spill (R5: FETCH 191 MB, 329 us). With (256,2) the cap
// is 256 regs and the kernel fits (R1/R3: 124 VGPR, zero spill).
__global__ __launch_bounds__(256, 2) void mega_kernel(
    const float* __restrict__ x, unsigned short* __restrict__ xbf,
    float* __restrict__ sq, float* __restrict__ pos_e,
    float* __restrict__ pos_d, float* __restrict__ tot_e,
    float* __restrict__ scal, float* __restrict__ out) {
  cg::grid_group grid = cg::this_grid();
  const int tid = threadIdx.x;
  const int lane = tid & 63;
  const int w = tid >> 6;  // wave 0..3
  const int b = blockIdx.x;

  __shared__ float xs[16][128];  // 8 KB: 2 classes = 16 rows
  __shared__ float sqs[16];
  __shared__ float part[4];
  __shared__ float s1[256], s2[256];

  // ===== phase A: bf16 convert + row norms + exact fp32 positives =========
  // block b: rows 16b..16b+15 (classes 2b, 2b+1); wave w: rows 4w..4w+3
  // (all 4 rows of a wave lie in one class -> partner loop is wave-uniform).
  {
#pragma unroll
    for (int rr = 0; rr < 4; ++rr) {
      int li = w * 4 + rr;
      int i = b * 16 + li;
      const float* xr = x + (size_t)i * DD;
      float a = xr[lane], cc = xr[lane + 64];
      xs[li][lane] = a;
      xs[li][lane + 64] = cc;
      float s = __fmaf_rn(a, a, cc * cc);
#pragma unroll
      for (int m = 32; m; m >>= 1) s += __shfl_xor(s, m, 64);
      if (lane == 0) {
        sq[i] = s;
        sqs[li] = s;
      }
      unsigned short* o = xbf + (size_t)i * DD;
      o[lane] = f2bf(a);
      o[lane + 64] = f2bf(cc);
    }
    if (tid < 16) tot_e[b * 16 + tid] = 0.f;
    if (b == 0 && tid == 0) scal[0] = 0.f;
    __syncthreads();
#pragma unroll
    for (int rr = 0; rr < 4; ++rr) {
      int li = w * 4 + rr;
      int i = b * 16 + li;
      int lb = li & ~7;  // class base within the 16 local rows
      float a = xs[li][lane], cc = xs[li][lane + 64];
      float sqi = sqs[li];
      float pe = 0.f, pd = 0.f;
#pragma unroll
      for (int j = lb; j < lb + 8; ++j) {
        if (j == li) continue;  // wave-uniform
        float dot = __fmaf_rn(a, xs[j][lane], cc * xs[j][lane + 64]);
#pragma unroll
        for (int m = 32; m; m >>= 1) dot += __shfl_xor(dot, m, 64);
        float d2 = fmaxf(__fmaf_rn(-2.f, dot, sqi + sqs[j]), 1e-12f);
        float dist = SQRTF(d2);
        pe += EXP2F(__fmaf_rn(dist, -C2, C2));
        pd += dist;
      }
      if (lane == 0) {
        pos_e[i] = pe;
        pos_d[i] = pd;
      }
    }
  }
  __threadfence();  // release xbf/sq before cross-XCD consumption
  grid.sync();
  __threadfence();  // acquire side: drop stale cached lines

  // ===== phase B: MFMA tiles (R1-proven 47us structure) ===================
  // logical grid (64,8): bx = rows 128, by = cols 1024. 4 waves in 2x2;
  // each wave a 64x64 tile = 4x4 of 16x16x32 MFMA, jt loop 8 x 128 cols.
  {
    const int bx = b & 63, by = b >> 6;
    const int q = lane >> 4, c = lane & 15;
    const int I0 = bx * 128 + (w >> 1) * 64;
    const int Jc = by * 1024 + (w & 1) * 64;

    bf16x8 afrag[4][4];
#pragma unroll
    for (int rb = 0; rb < 4; ++rb) {
      const unsigned short* ap = xbf + (size_t)(I0 + rb * 16 + c) * DD + q * 8;
#pragma unroll
      for (int ks = 0; ks < 4; ++ks)
        afrag[rb][ks] = *(const bf16x8*)(ap + ks * 32);
    }
    float sqi[16];
#pragma unroll
    for (int rb = 0; rb < 4; ++rb)
#pragma unroll
      for (int r = 0; r < 4; ++r)
        sqi[rb * 4 + r] = sq[I0 + rb * 16 + q * 4 + r];

    float tote[16];
#pragma unroll
    for (int k = 0; k < 16; ++k) tote[k] = 0.f;
    float totd = 0.f;

    for (int jt = 0; jt < 8; ++jt) {
      int J0 = Jc + jt * 128;
      f32x4 acc[4][4];
#pragma unroll
      for (int rb = 0; rb < 4; ++rb)
#pragma unroll
        for (int cb = 0; cb < 4; ++cb)
          acc[rb][cb] = (f32x4){0.f, 0.f, 0.f, 0.f};
#pragma unroll
      for (int ks = 0; ks < 4; ++ks) {
        bf16x8 bfr[4];
#pragma unroll
        for (int cb = 0; cb < 4; ++cb)
          bfr[cb] = *(const bf16x8*)(xbf + (size_t)(J0 + cb * 16 + c) * DD +
                                     ks * 32 + q * 8);
#pragma unroll
        for (int rb = 0; rb < 4; ++rb)
#pragma unroll
          for (int cb = 0; cb < 4; ++cb)
            acc[rb][cb] = __builtin_amdgcn_mfma_f32_16x16x32_bf16(
                afrag[rb][ks], bfr[cb], acc[rb][cb], 0, 0, 0);
      }
      // epilogue: C/D mapping col = lane&15, row = q*4 + reg (m89-verified)
      float sqj[4];
#pragma unroll
      for (int cb = 0; cb < 4; ++cb) sqj[cb] = sq[J0 + cb * 16 + c];
#pragma unroll
      for (int rb = 0; rb < 4; ++rb) {
#pragma unroll
        for (int cb = 0; cb < 4; ++cb) {
          bool diag = (I0 + rb * 16) == (J0 + cb * 16);
#pragma unroll
          for (int r = 0; r < 4; ++r) {
            float d2 = fmaxf(
                __fmaf_rn(-2.f, acc[rb][cb][r], sqi[rb * 4 + r] + sqj[cb]),
                1e-12f);
            float dist = SQRTF(d2);
            float ex = EXP2F(__fmaf_rn(dist, -C2, C2));
            if (diag && (q * 4 + r) == c) {  // exclude self-pair
              ex = 0.f;
              dist = 0.f;
            }
            tote[rb * 4 + r] += ex;
            totd += dist;
          }
        }
      }
    }

#pragma unroll
    for (int k = 0; k < 16; ++k) {
      float v = tote[k];
      v += __shfl_xor(v, 1, 64);
      v += __shfl_xor(v, 2, 64);
      v += __shfl_xor(v, 4, 64);
      v += __shfl_xor(v, 8, 64);
      tote[k] = v;
    }
    if (c == 0) {
#pragma unroll
      for (int rb = 0; rb < 4; ++rb)
#pragma unroll
        for (int r = 0; r < 4; ++r)
          atomicAdd(&tot_e[I0 + rb * 16 + q * 4 + r], tote[rb * 4 + r]);
    }
#pragma unroll
    for (int m = 32; m; m >>= 1) totd += __shfl_xor(totd, m, 64);
    if (lane == 0) part[w] = totd;
    __syncthreads();
    if (tid == 0) atomicAdd(&scal[0], part[0] + part[1] + part[2] + part[3]);
  }
  __threadfence();
  grid.sync();

  // ===== phase C: final scalars (block 0) =================================
  if (b == 0) {
    float lsum = 0.f, pdsum = 0.f;
    for (int i = tid; i < NN; i += 256) {
      // agent-scope atomic loads: coherent reads of cross-XCD accumulations
      float p = __hip_atomic_load(&pos_e[i], __ATOMIC_RELAXED,
                                  __HIP_MEMORY_SCOPE_AGENT);
      float t = __hip_atomic_load(&tot_e[i], __ATOMIC_RELAXED,
                                  __HIP_MEMORY_SCOPE_AGENT);
      float pdv = __hip_atomic_load(&pos_d[i], __ATOMIC_RELAXED,
                                    __HIP_MEMORY_SCOPE_AGENT);
      float denom = __fmaf_rn(0.5f, t - p, p);  // p + 0.5*(tot - p)
      lsum += LOG2F(denom) - LOG2F(p);          // -log2(p/(p+neg))
      pdsum += pdv;
    }
    s1[tid] = lsum;
    s2[tid] = pdsum;
    __syncthreads();
    for (int ww = 128; ww; ww >>= 1) {
      if (tid < ww) {
        s1[tid] += s1[tid + ww];
        s2[tid] += s2[tid + ww];
      }
      __syncthreads();
    }
    if (tid == 0) {
      float sc = __hip_atomic_load(&scal[0], __ATOMIC_RELAXED,
                                   __HIP_MEMORY_SCOPE_AGENT);
      out[0] = s1[0] * LN2 / (float)NN;              // loss
      out[1] = 1.0f;                                 // prec
      out[2] = s2[0] / (float)(NN * 7);              // pos_d
      out[3] = (sc - s2[0]) / ((float)NN * 8184.f);  // neg_d
    }
  }
}

// ======================= fallback path (R1/R3-proven) ======================
__global__ __launch_bounds__(512) void prep_pos_kernel(
    const float* __restrict__ x, unsigned short* __restrict__ xbf,
    float* __restrict__ sq, float* __restrict__ pos_e,
    float* __restrict__ pos_d, float* __restrict__ tot_e,
    float* __restrict__ scal) {
  int w = threadIdx.x >> 6;
  int lane = threadIdx.x & 63;
  int i = blockIdx.x * 8 + w;

  __shared__ float xs[8][128];
  __shared__ float sqs[8];

  const float* xr = x + (size_t)i * DD;
  float a = xr[lane], cc = xr[lane + 64];
  xs[w][lane] = a;
  xs[w][lane + 64] = cc;

  float s = __fmaf_rn(a, a, cc * cc);
#pragma unroll
  for (int m = 32; m; m >>= 1) s += __shfl_xor(s, m, 64);
  if (lane == 0) {
    sq[i] = s;
    sqs[w] = s;
  }
  unsigned short* o = xbf + (size_t)i * DD;
  o[lane] = f2bf(a);
  o[lane + 64] = f2bf(cc);
  if (lane == 1) tot_e[i] = 0.f;
  if (blockIdx.x == 0 && threadIdx.x == 0) scal[0] = 0.f;

  __syncthreads();
  float sqi = sqs[w];
  float pe = 0.f, pd = 0.f;
  for (int j = 0; j < 8; ++j) {
    if (j == w) continue;
    float dot = __fmaf_rn(a, xs[j][lane], cc * xs[j][lane + 64]);
#pragma unroll
    for (int m = 32; m; m >>= 1) dot += __shfl_xor(dot, m, 64);
    float d2 = fmaxf(__fmaf_rn(-2.f, dot, sqi + sqs[j]), 1e-12f);
    float dist = SQRTF(d2);
    pe += EXP2F(__fmaf_rn(dist, -C2, C2));
    pd += dist;
  }
  if (lane == 0) {
    pos_e[i] = pe;
    pos_d[i] = pd;
  }
}

__global__ __launch_bounds__(256, 2) void tile_kernel(
    const unsigned short* __restrict__ xbf, const float* __restrict__ sq,
    float* __restrict__ tot_e, float* __restrict__ scal) {
  int lane = threadIdx.x & 63;
  int wave = threadIdx.x >> 6;
  int q = lane >> 4, c = lane & 15;
  int I0 = blockIdx.x * 128 + (wave >> 1) * 64;
  int Jc = blockIdx.y * 1024 + (wave & 1) * 64;

  bf16x8 afrag[4][4];
#pragma unroll
  for (int rb = 0; rb < 4; ++rb) {
    const unsigned short* ap = xbf + (size_t)(I0 + rb * 16 + c) * DD + q * 8;
#pragma unroll
    for (int ks = 0; ks < 4; ++ks)
      afrag[rb][ks] = *(const bf16x8*)(ap + ks * 32);
  }
  float sqi[16];
#pragma unroll
  for (int rb = 0; rb < 4; ++rb)
#pragma unroll
    for (int r = 0; r < 4; ++r)
      sqi[rb * 4 + r] = sq[I0 + rb * 16 + q * 4 + r];

  float tote[16];
#pragma unroll
  for (int k = 0; k < 16; ++k) tote[k] = 0.f;
  float totd = 0.f;

  for (int jt = 0; jt < 8; ++jt) {
    int J0 = Jc + jt * 128;
    f32x4 acc[4][4];
#pragma unroll
    for (int rb = 0; rb < 4; ++rb)
#pragma unroll
      for (int cb = 0; cb < 4; ++cb) acc[rb][cb] = (f32x4){0.f, 0.f, 0.f, 0.f};
#pragma unroll
    for (int ks = 0; ks < 4; ++ks) {
      bf16x8 bfr[4];
#pragma unroll
      for (int cb = 0; cb < 4; ++cb)
        bfr[cb] = *(const bf16x8*)(xbf + (size_t)(J0 + cb * 16 + c) * DD +
                                   ks * 32 + q * 8);
#pragma unroll
      for (int rb = 0; rb < 4; ++rb)
#pragma unroll
        for (int cb = 0; cb < 4; ++cb)
          acc[rb][cb] = __builtin_amdgcn_mfma_f32_16x16x32_bf16(
              afrag[rb][ks], bfr[cb], acc[rb][cb], 0, 0, 0);
    }
    float sqj[4];
#pragma unroll
    for (int cb = 0; cb < 4; ++cb) sqj[cb] = sq[J0 + cb * 16 + c];
#pragma unroll
    for (int rb = 0; rb < 4; ++rb) {
#pragma unroll
      for (int cb = 0; cb < 4; ++cb) {
        bool diag = (I0 + rb * 16) == (J0 + cb * 16);
#pragma unroll
        for (int r = 0; r < 4; ++r) {
          float d2 = fmaxf(
              __fmaf_rn(-2.f, acc[rb][cb][r], sqi[rb * 4 + r] + sqj[cb]),
              1e-12f);
          float dist = SQRTF(d2);
          float ex = EXP2F(__fmaf_rn(dist, -C2, C2));
          if (diag && (q * 4 + r) == c) {
            ex = 0.f;
            dist = 0.f;
          }
          tote[rb * 4 + r] += ex;
          totd += dist;
        }
      }
    }
  }

#pragma unroll
  for (int k = 0; k < 16; ++k) {
    float v = tote[k];
    v += __shfl_xor(v, 1, 64);
    v += __shfl_xor(v, 2, 64);
    v += __shfl_xor(v, 4, 64);
    v += __shfl_xor(v, 8, 64);
    tote[k] = v;
  }
  if (c == 0) {
#pragma unroll
    for (int rb = 0; rb < 4; ++rb)
#pragma unroll
      for (int r = 0; r < 4; ++r)
        atomicAdd(&tot_e[I0 + rb * 16 + q * 4 + r], tote[rb * 4 + r]);
  }
#pragma unroll
  for (int m = 32; m; m >>= 1) totd += __shfl_xor(totd, m, 64);
  __shared__ float part[4];
  if (lane == 0) part[wave] = totd;
  __syncthreads();
  if (threadIdx.x == 0)
    atomicAdd(&scal[0], part[0] + part[1] + part[2] + part[3]);
}

__global__ void fin_kernel(const float* __restrict__ tot_e,
                           const float* __restrict__ pos_e,
                           const float* __restrict__ pos_d,
                           const float* __restrict__ scal,
                           float* __restrict__ out) {
  int tid = threadIdx.x;
  float lsum = 0.f, pdsum = 0.f;
  for (int i = tid; i < NN; i += 256) {
    float p = pos_e[i];
    float t = tot_e[i];
    float denom = __fmaf_rn(0.5f, t - p, p);
    lsum += LOG2F(denom) - LOG2F(p);
    pdsum += pos_d[i];
  }
  __shared__ float s1[256], s2[256];
  s1[tid] = lsum;
  s2[tid] = pdsum;
  __syncthreads();
  for (int w = 128; w; w >>= 1) {
    if (tid < w) {
      s1[tid] += s1[tid + w];
      s2[tid] += s2[tid + w];
    }
    __syncthreads();
  }
  if (tid == 0) {
    out[0] = s1[0] * LN2 / (float)NN;
    out[1] = 1.0f;
    out[2] = s2[0] / (float)(NN * 7);
    out[3] = (scal[0] - s2[0]) / ((float)NN * 8184.f);
  }
}

extern "C" void kernel_launch(void* const* d_in, const int* in_sizes, int n_in,
                              void* d_out, int out_size, void* d_ws,
                              size_t ws_size, hipStream_t stream) {
  const float* x = (const float*)d_in[0];
  float* out = (float*)d_out;
  char* ws = (char*)d_ws;

  unsigned short* xbf = (unsigned short*)ws;       // 2 MB
  float* sq = (float*)(ws + (size_t)NN * DD * 2);  // 32 KB each
  float* tot_e = sq + NN;
  float* pos_e = tot_e + NN;
  float* pos_d = pos_e + NN;
  float* scal = pos_d + NN;  // [0] = total dist sum

  void* args[] = {(void*)&x,     (void*)&xbf,   (void*)&sq,
                  (void*)&pos_e, (void*)&pos_d, (void*)&tot_e,
                  (void*)&scal,  (void*)&out};
  hipError_t err = hipLaunchCooperativeKernel(
      (const void*)mega_kernel, dim3(512), dim3(256), args, 0, stream);
  if (err != hipSuccess) {
    // deterministic fallback: proven 3-kernel path (same math, R1/R3)
    prep_pos_kernel<<<NN / 8, 512, 0, stream>>>(x, xbf, sq, pos_e, pos_d,
                                                tot_e, scal);
    tile_kernel<<<dim3(64, 8), 256, 0, stream>>>(xbf, sq, tot_e, scal);
    fin_kernel<<<1, 256, 0, stream>>>(tot_e, pos_e, pos_d, scal, out);
  }
}

// Round 7
// 147.043 us; speedup vs baseline: 2.6481x; 2.0788x over previous
//
#include <hip/hip_runtime.h>

#define NN 8192
#define DD 128
// ALPHA * log2(e)
#define C2 72.13475204444817f
#define LN2 0.6931471805599453f

typedef __attribute__((ext_vector_type(8))) __bf16 bf16x8;
typedef __attribute__((ext_vector_type(4))) float f32x4;

#if __has_builtin(__builtin_amdgcn_exp2f)
#define EXP2F(x) __builtin_amdgcn_exp2f(x)
#else
#define EXP2F(x) exp2f(x)
#endif
#if __has_builtin(__builtin_amdgcn_sqrtf)
#define SQRTF(x) __builtin_amdgcn_sqrtf(x)
#else
#define SQRTF(x) sqrtf(x)
#endif
#if __has_builtin(__builtin_amdgcn_logf)
#define LOG2F(x) __builtin_amdgcn_logf(x)  // v_log_f32 = log base 2
#else
#define LOG2F(x) log2f(x)
#endif

__device__ __forceinline__ unsigned short f2bf(float f) {
  unsigned u = __float_as_uint(f);
  u += 0x7FFFu + ((u >> 16) & 1u);  // RNE
  return (unsigned short)(u >> 16);
}

// ------- kernel A: fused bf16-convert + row norms + exact fp32 positives ----
// block = 512 threads = 8 waves = one class (targets are arange(N)//8).
// Also zeroes tot_e (per-row) and scal (block 0): no memset dispatch needed.
// (R1-proven; cooperative mega-kernel abandoned: grid.sync() at 512 blocks
// cost ~190 us of pure idle — R6: 243 us @ VALUBusy 9%.)
__global__ __launch_bounds__(512) void prep_pos_kernel(
    const float* __restrict__ x, unsigned short* __restrict__ xbf,
    float* __restrict__ sq, float* __restrict__ pos_e,
    float* __restrict__ pos_d, float* __restrict__ tot_e,
    float* __restrict__ scal) {
  int w = threadIdx.x >> 6;
  int lane = threadIdx.x & 63;
  int i = blockIdx.x * 8 + w;

  __shared__ float xs[8][128];
  __shared__ float sqs[8];

  const float* xr = x + (size_t)i * DD;
  float a = xr[lane], cc = xr[lane + 64];
  xs[w][lane] = a;
  xs[w][lane + 64] = cc;

  float s = __fmaf_rn(a, a, cc * cc);
#pragma unroll
  for (int m = 32; m; m >>= 1) s += __shfl_xor(s, m, 64);
  if (lane == 0) {
    sq[i] = s;
    sqs[w] = s;
  }
  unsigned short* o = xbf + (size_t)i * DD;
  o[lane] = f2bf(a);
  o[lane + 64] = f2bf(cc);
  if (lane == 1) tot_e[i] = 0.f;
  if (blockIdx.x == 0 && threadIdx.x == 0) scal[0] = 0.f;

  __syncthreads();
  float sqi = sqs[w];
  float pe = 0.f, pd = 0.f;
  for (int j = 0; j < 8; ++j) {
    if (j == w) continue;  // wave-uniform
    float dot = __fmaf_rn(a, xs[j][lane], cc * xs[j][lane + 64]);
#pragma unroll
    for (int m = 32; m; m >>= 1) dot += __shfl_xor(dot, m, 64);
    float d2 = fmaxf(__fmaf_rn(-2.f, dot, sqi + sqs[j]), 1e-12f);
    float dist = SQRTF(d2);
    pe += EXP2F(__fmaf_rn(dist, -C2, C2));
    pd += dist;
  }
  if (lane == 0) {
    pos_e[i] = pe;
    pos_d[i] = pd;
  }
}

// ---------------- kernel B: MFMA tile kernel v2 --------------------------
// grid (64,16) = 1024 blocks = 4 blocks/CU = 4 waves/SIMD (vs R1's 2).
// Wave tile shrunk 64x64 -> 32x64 so the footprint fits launch_bounds(256,4)'s
// 128-reg unified cap WITHOUT spilling: afrag[2][4]=32 + acc[2][4]=32 +
// bfr[4]=16 + tote/sqi/addr ~ 110 regs. (R2 lesson: the 64x64 structure
// needs ~188 regs; forcing it under 128 spilled 300 MB. This one fits.)
// block (bx,by): rows bx*128 (wave w: 32 rows), cols by*512 (jt: 8 x 64).
__global__ __launch_bounds__(256, 4) void tile_kernel(
    const unsigned short* __restrict__ xbf, const float* __restrict__ sq,
    float* __restrict__ tot_e, float* __restrict__ scal) {
  int lane = threadIdx.x & 63;
  int wave = threadIdx.x >> 6;
  int q = lane >> 4, c = lane & 15;
  int I0 = blockIdx.x * 128 + wave * 32;  // wave row base (2 rb of 16)
  int Jc = blockIdx.y * 512;              // block col chunk

  // A fragments: A[m = lane&15][k = q*8 + j] -> 16B contiguous per lane
  bf16x8 afrag[2][4];
#pragma unroll
  for (int rb = 0; rb < 2; ++rb) {
    const unsigned short* ap = xbf + (size_t)(I0 + rb * 16 + c) * DD + q * 8;
#pragma unroll
    for (int ks = 0; ks < 4; ++ks)
      afrag[rb][ks] = *(const bf16x8*)(ap + ks * 32);
  }
  float sqi[8];
#pragma unroll
  for (int rb = 0; rb < 2; ++rb)
#pragma unroll
    for (int r = 0; r < 4; ++r)
      sqi[rb * 4 + r] = sq[I0 + rb * 16 + q * 4 + r];

  float tote[8];
#pragma unroll
  for (int k = 0; k < 8; ++k) tote[k] = 0.f;
  float totd = 0.f;

  for (int jt = 0; jt < 8; ++jt) {
    int J0 = Jc + jt * 64;
    f32x4 acc[2][4];
#pragma unroll
    for (int rb = 0; rb < 2; ++rb)
#pragma unroll
      for (int cb = 0; cb < 4; ++cb) acc[rb][cb] = (f32x4){0.f, 0.f, 0.f, 0.f};
#pragma unroll
    for (int ks = 0; ks < 4; ++ks) {
      bf16x8 bfr[4];  // B = X^T: B-frag loads identically from X rows
#pragma unroll
      for (int cb = 0; cb < 4; ++cb)
        bfr[cb] = *(const bf16x8*)(xbf + (size_t)(J0 + cb * 16 + c) * DD +
                                   ks * 32 + q * 8);
#pragma unroll
      for (int rb = 0; rb < 2; ++rb)
#pragma unroll
        for (int cb = 0; cb < 4; ++cb)
          acc[rb][cb] = __builtin_amdgcn_mfma_f32_16x16x32_bf16(
              afrag[rb][ks], bfr[cb], acc[rb][cb], 0, 0, 0);
    }
    // epilogue: C/D mapping col = lane&15, row = q*4 + reg (m89-verified)
    float sqj[4];
#pragma unroll
    for (int cb = 0; cb < 4; ++cb) sqj[cb] = sq[J0 + cb * 16 + c];
#pragma unroll
    for (int rb = 0; rb < 2; ++rb) {
#pragma unroll
      for (int cb = 0; cb < 4; ++cb) {
        bool diag = (I0 + rb * 16) == (J0 + cb * 16);
#pragma unroll
        for (int r = 0; r < 4; ++r) {
          float d2 = fmaxf(
              __fmaf_rn(-2.f, acc[rb][cb][r], sqi[rb * 4 + r] + sqj[cb]),
              1e-12f);
          float dist = SQRTF(d2);
          float ex = EXP2F(__fmaf_rn(dist, -C2, C2));
          if (diag && (q * 4 + r) == c) {  // exclude self-pair
            ex = 0.f;
            dist = 0.f;
          }
          tote[rb * 4 + r] += ex;
          totd += dist;
        }
      }
    }
  }

  // reduce row sums across the 16 column-lanes (lane bits 0..3)
#pragma unroll
  for (int k = 0; k < 8; ++k) {
    float v = tote[k];
    v += __shfl_xor(v, 1, 64);
    v += __shfl_xor(v, 2, 64);
    v += __shfl_xor(v, 4, 64);
    v += __shfl_xor(v, 8, 64);
    tote[k] = v;
  }
  if (c == 0) {
#pragma unroll
    for (int rb = 0; rb < 2; ++rb)
#pragma unroll
      for (int r = 0; r < 4; ++r)
        atomicAdd(&tot_e[I0 + rb * 16 + q * 4 + r], tote[rb * 4 + r]);
  }
  // global dist sum: wave reduce -> block reduce -> one atomic per block
#pragma unroll
  for (int m = 32; m; m >>= 1) totd += __shfl_xor(totd, m, 64);
  __shared__ float part[4];
  if (lane == 0) part[wave] = totd;
  __syncthreads();
  if (threadIdx.x == 0)
    atomicAdd(&scal[0], part[0] + part[1] + part[2] + part[3]);
}

// ---------------- kernel C: final scalars --------------------------------
__global__ void fin_kernel(const float* __restrict__ tot_e,
                           const float* __restrict__ pos_e,
                           const float* __restrict__ pos_d,
                           const float* __restrict__ scal,
                           float* __restrict__ out) {
  int tid = threadIdx.x;
  float lsum = 0.f, pdsum = 0.f;
  for (int i = tid; i < NN; i += 256) {
    float p = pos_e[i];
    float t = tot_e[i];
    float denom = __fmaf_rn(0.5f, t - p, p);  // p + 0.5*(tot - p)
    lsum += LOG2F(denom) - LOG2F(p);          // -log2(p/(p+neg))
    pdsum += pos_d[i];
  }
  __shared__ float s1[256], s2[256];
  s1[tid] = lsum;
  s2[tid] = pdsum;
  __syncthreads();
  for (int w = 128; w; w >>= 1) {
    if (tid < w) {
      s1[tid] += s1[tid + w];
      s2[tid] += s2[tid + w];
    }
    __syncthreads();
  }
  if (tid == 0) {
    out[0] = s1[0] * LN2 / (float)NN;                   // loss
    out[1] = 1.0f;                                      // prec
    out[2] = s2[0] / (float)(NN * 7);                   // pos_d
    out[3] = (scal[0] - s2[0]) / ((float)NN * 8184.f);  // neg_d
  }
}

extern "C" void kernel_launch(void* const* d_in, const int* in_sizes, int n_in,
                              void* d_out, int out_size, void* d_ws,
                              size_t ws_size, hipStream_t stream) {
  const float* x = (const float*)d_in[0];
  float* out = (float*)d_out;
  char* ws = (char*)d_ws;

  unsigned short* xbf = (unsigned short*)ws;       // 2 MB
  float* sq = (float*)(ws + (size_t)NN * DD * 2);  // 32 KB each
  float* tot_e = sq + NN;
  float* pos_e = tot_e + NN;
  float* pos_d = pos_e + NN;
  float* scal = pos_d + NN;  // [0] = total dist sum

  prep_pos_kernel<<<NN / 8, 512, 0, stream>>>(x, xbf, sq, pos_e, pos_d, tot_e,
                                              scal);
  tile_kernel<<<dim3(64, 16), 256, 0, stream>>>(xbf, sq, tot_e, scal);
  fin_kernel<<<1, 256, 0, stream>>>(tot_e, pos_e, pos_d, scal, out);
}

// Round 8
// 128.535 us; speedup vs baseline: 3.0294x; 1.1440x over previous
//
#include <hip/hip_runtime.h>

#define NN 8192
#define DD 128
// ALPHA * log2(e)
#define C2 72.13475204444817f
#define LN2 0.6931471805599453f

typedef __attribute__((ext_vector_type(8))) __bf16 bf16x8;
typedef __attribute__((ext_vector_type(4))) float f32x4;

#if __has_builtin(__builtin_amdgcn_exp2f)
#define EXP2F(x) __builtin_amdgcn_exp2f(x)
#else
#define EXP2F(x) exp2f(x)
#endif
#if __has_builtin(__builtin_amdgcn_sqrtf)
#define SQRTF(x) __builtin_amdgcn_sqrtf(x)
#else
#define SQRTF(x) sqrtf(x)
#endif
#if __has_builtin(__builtin_amdgcn_logf)
#define LOG2F(x) __builtin_amdgcn_logf(x)  // v_log_f32 = log base 2
#else
#define LOG2F(x) log2f(x)
#endif

__device__ __forceinline__ unsigned short f2bf(float f) {
  unsigned u = __float_as_uint(f);
  u += 0x7FFFu + ((u >> 16) & 1u);  // RNE
  return (unsigned short)(u >> 16);
}

// ------- kernel A: fused bf16-convert + row norms + exact fp32 positives ----
// block = 512 threads = 8 waves = one class (targets are arange(N)//8).
// Also zeroes tot_e (per-row) and scal (block 0): no memset dispatch needed.
__global__ __launch_bounds__(512) void prep_pos_kernel(
    const float* __restrict__ x, unsigned short* __restrict__ xbf,
    float* __restrict__ sq, float* __restrict__ pos_e,
    float* __restrict__ pos_d, float* __restrict__ tot_e,
    float* __restrict__ scal) {
  int w = threadIdx.x >> 6;
  int lane = threadIdx.x & 63;
  int i = blockIdx.x * 8 + w;

  __shared__ float xs[8][128];
  __shared__ float sqs[8];

  const float* xr = x + (size_t)i * DD;
  float a = xr[lane], cc = xr[lane + 64];
  xs[w][lane] = a;
  xs[w][lane + 64] = cc;

  float s = __fmaf_rn(a, a, cc * cc);
#pragma unroll
  for (int m = 32; m; m >>= 1) s += __shfl_xor(s, m, 64);
  if (lane == 0) {
    sq[i] = s;
    sqs[w] = s;
  }
  unsigned short* o = xbf + (size_t)i * DD;
  o[lane] = f2bf(a);
  o[lane + 64] = f2bf(cc);
  if (lane == 1) tot_e[i] = 0.f;
  if (blockIdx.x == 0 && threadIdx.x == 0) scal[0] = 0.f;

  __syncthreads();
  float sqi = sqs[w];
  float pe = 0.f, pd = 0.f;
  for (int j = 0; j < 8; ++j) {
    if (j == w) continue;  // wave-uniform
    float dot = __fmaf_rn(a, xs[j][lane], cc * xs[j][lane + 64]);
#pragma unroll
    for (int m = 32; m; m >>= 1) dot += __shfl_xor(dot, m, 64);
    float d2 = fmaxf(__fmaf_rn(-2.f, dot, sqi + sqs[j]), 1e-12f);
    float dist = SQRTF(d2);
    pe += EXP2F(__fmaf_rn(dist, -C2, C2));
    pd += dist;
  }
  if (lane == 0) {
    pos_e[i] = pe;
    pos_d[i] = pd;
  }
}

// ---------------- kernel B: MFMA tile kernel v3 --------------------------
// R7 lesson: occupancy alone isn't the lever — per-wave reuse (4 rows per
// B-frag) and register room for load pipelining are. Keep R1's 64-row wave
// tile; get 3 waves/SIMD (vs R1's 2) by halving live accumulator state:
// per jt the 64 cols are processed in two cb-halves (acc[4][2]=32 regs,
// bfr[2]=8) at zero extra B-traffic. Est. ~156 regs <= 170 cap of (256,3).
// grid (64,16): block = 128 rows x 512 cols; wave = 64 rows x 256 cols
// (2x2 wave layout), jt = 4 x 64-col tiles.
// Diagonal specialization: only blocks with bx>>2 == by can contain
// self-pairs; the other 960/1024 run a cndmask-free epilogue.
__global__ __launch_bounds__(256, 3) void tile_kernel(
    const unsigned short* __restrict__ xbf, const float* __restrict__ sq,
    float* __restrict__ tot_e, float* __restrict__ scal) {
  int lane = threadIdx.x & 63;
  int wave = threadIdx.x >> 6;
  int q = lane >> 4, c = lane & 15;
  int I0 = blockIdx.x * 128 + (wave >> 1) * 64;   // wave row base
  int Jb = blockIdx.y * 512 + (wave & 1) * 256;   // wave col strip
  const bool hasDiag = ((int)(blockIdx.x >> 2) == (int)blockIdx.y);

  // A fragments: A[m = lane&15][k = q*8 + j] -> 16B contiguous per lane
  bf16x8 afrag[4][4];
#pragma unroll
  for (int rb = 0; rb < 4; ++rb) {
    const unsigned short* ap = xbf + (size_t)(I0 + rb * 16 + c) * DD + q * 8;
#pragma unroll
    for (int ks = 0; ks < 4; ++ks)
      afrag[rb][ks] = *(const bf16x8*)(ap + ks * 32);
  }
  float sqi[16];
#pragma unroll
  for (int rb = 0; rb < 4; ++rb) {
    f32x4 v = *(const f32x4*)(sq + I0 + rb * 16 + q * 4);
#pragma unroll
    for (int r = 0; r < 4; ++r) sqi[rb * 4 + r] = v[r];
  }

  float tote[16];
#pragma unroll
  for (int k = 0; k < 16; ++k) tote[k] = 0.f;
  float totd = 0.f;

// epilogue body over one cb-half; DIAGF is compile-time-ish (macro expanded
// under a wave-uniform branch) so the false version has no cndmasks.
#define EPI_HALF(DIAGF)                                                       \
  do {                                                                        \
    _Pragma("unroll") for (int rb = 0; rb < 4; ++rb) {                        \
      _Pragma("unroll") for (int cb = 0; cb < 2; ++cb) {                      \
        bool diag = DIAGF && ((I0 + rb * 16) == (J0 + (cb0 + cb) * 16));      \
        _Pragma("unroll") for (int r = 0; r < 4; ++r) {                       \
          float d2 = fmaxf(                                                   \
              __fmaf_rn(-2.f, acc[rb][cb][r], sqi[rb * 4 + r] + sqj[cb]),     \
              1e-12f);                                                        \
          float dist = SQRTF(d2);                                             \
          float ex = EXP2F(__fmaf_rn(dist, -C2, C2));                         \
          if (DIAGF) {                                                        \
            if (diag && (q * 4 + r) == c) {                                   \
              ex = 0.f;                                                       \
              dist = 0.f;                                                     \
            }                                                                 \
          }                                                                   \
          tote[rb * 4 + r] += ex;                                             \
          totd += dist;                                                       \
        }                                                                     \
      }                                                                       \
    }                                                                         \
  } while (0)

  for (int jt = 0; jt < 4; ++jt) {
    int J0 = Jb + jt * 64;
#pragma unroll
    for (int h = 0; h < 2; ++h) {
      int cb0 = h * 2;
      f32x4 acc[4][2];
#pragma unroll
      for (int rb = 0; rb < 4; ++rb)
#pragma unroll
        for (int cb = 0; cb < 2; ++cb)
          acc[rb][cb] = (f32x4){0.f, 0.f, 0.f, 0.f};
#pragma unroll
      for (int ks = 0; ks < 4; ++ks) {
        bf16x8 bfr[2];  // B = X^T: B-frag loads identically from X rows
#pragma unroll
        for (int cb = 0; cb < 2; ++cb)
          bfr[cb] =
              *(const bf16x8*)(xbf + (size_t)(J0 + (cb0 + cb) * 16 + c) * DD +
                               ks * 32 + q * 8);
#pragma unroll
        for (int rb = 0; rb < 4; ++rb)
#pragma unroll
          for (int cb = 0; cb < 2; ++cb)
            acc[rb][cb] = __builtin_amdgcn_mfma_f32_16x16x32_bf16(
                afrag[rb][ks], bfr[cb], acc[rb][cb], 0, 0, 0);
      }
      // epilogue: C/D mapping col = lane&15, row = q*4 + reg (m89-verified)
      float sqj[2];
#pragma unroll
      for (int cb = 0; cb < 2; ++cb) sqj[cb] = sq[J0 + (cb0 + cb) * 16 + c];
      if (hasDiag) {
        EPI_HALF(true);
      } else {
        EPI_HALF(false);
      }
    }
  }
#undef EPI_HALF

  // reduce row sums across the 16 column-lanes (lane bits 0..3)
#pragma unroll
  for (int k = 0; k < 16; ++k) {
    float v = tote[k];
    v += __shfl_xor(v, 1, 64);
    v += __shfl_xor(v, 2, 64);
    v += __shfl_xor(v, 4, 64);
    v += __shfl_xor(v, 8, 64);
    tote[k] = v;
  }
  if (c == 0) {
#pragma unroll
    for (int rb = 0; rb < 4; ++rb)
#pragma unroll
      for (int r = 0; r < 4; ++r)
        atomicAdd(&tot_e[I0 + rb * 16 + q * 4 + r], tote[rb * 4 + r]);
  }
  // global dist sum: wave reduce -> block reduce -> one atomic per block
#pragma unroll
  for (int m = 32; m; m >>= 1) totd += __shfl_xor(totd, m, 64);
  __shared__ float part[4];
  if (lane == 0) part[wave] = totd;
  __syncthreads();
  if (threadIdx.x == 0)
    atomicAdd(&scal[0], part[0] + part[1] + part[2] + part[3]);
}

// ---------------- kernel C: final scalars --------------------------------
__global__ void fin_kernel(const float* __restrict__ tot_e,
                           const float* __restrict__ pos_e,
                           const float* __restrict__ pos_d,
                           const float* __restrict__ scal,
                           float* __restrict__ out) {
  int tid = threadIdx.x;
  float lsum = 0.f, pdsum = 0.f;
  for (int i = tid; i < NN; i += 256) {
    float p = pos_e[i];
    float t = tot_e[i];
    float denom = __fmaf_rn(0.5f, t - p, p);  // p + 0.5*(tot - p)
    lsum += LOG2F(denom) - LOG2F(p);          // -log2(p/(p+neg))
    pdsum += pos_d[i];
  }
  __shared__ float s1[256], s2[256];
  s1[tid] = lsum;
  s2[tid] = pdsum;
  __syncthreads();
  for (int w = 128; w; w >>= 1) {
    if (tid < w) {
      s1[tid] += s1[tid + w];
      s2[tid] += s2[tid + w];
    }
    __syncthreads();
  }
  if (tid == 0) {
    out[0] = s1[0] * LN2 / (float)NN;                   // loss
    out[1] = 1.0f;                                      // prec
    out[2] = s2[0] / (float)(NN * 7);                   // pos_d
    out[3] = (scal[0] - s2[0]) / ((float)NN * 8184.f);  // neg_d
  }
}

extern "C" void kernel_launch(void* const* d_in, const int* in_sizes, int n_in,
                              void* d_out, int out_size, void* d_ws,
                              size_t ws_size, hipStream_t stream) {
  const float* x = (const float*)d_in[0];
  float* out = (float*)d_out;
  char* ws = (char*)d_ws;

  unsigned short* xbf = (unsigned short*)ws;       // 2 MB
  float* sq = (float*)(ws + (size_t)NN * DD * 2);  // 32 KB each
  float* tot_e = sq + NN;
  float* pos_e = tot_e + NN;
  float* pos_d = pos_e + NN;
  float* scal = pos_d + NN;  // [0] = total dist sum

  prep_pos_kernel<<<NN / 8, 512, 0, stream>>>(x, xbf, sq, pos_e, pos_d, tot_e,
                                              scal);
  tile_kernel<<<dim3(64, 16), 256, 0, stream>>>(xbf, sq, tot_e, scal);
  fin_kernel<<<1, 256, 0, stream>>>(tot_e, pos_e, pos_d, scal, out);
}